// Round 9
// baseline (189.724 us; speedup 1.0000x reference)
//
#include <hip/hip_runtime.h>
#include <hip/hip_fp16.h>

#define IN_DIM 29
#define XDIM 32
#define OUT_DIM 64
#define BN_EPS 1e-5f

#define BW      32       // dsts per bucket
#define BW_LOG  5
#define TNODES  64       // nodes per transform block (stage = 64*32*4 = 8 KB)
#define MAXBUCK 4096     // static LDS arrays; n_nodes <= 131072
#define MAXNBLK 128      // count/partition chunks (pool LDS tables sized to this)
#define KCAP    4096     // pool: max keys assembled in LDS (16 KB)
#define SENT    0        // ordered-u16 sentinel: any real enc > 0

// ===========================================================================
// out[d][o] = max_{src in N(d)} y[src][o] + (beta - a*mean - a*(W[:,29:32].node_d))[o]
// y[n][o] = a[o] * (W[o,:] . [feat_n; node_n]),  a = gamma*rsqrt(var+eps)
// y stored as monotone ordered-u16 fp16 encoding; empty segment -> 0.
//
// Two-kernel pipeline:
//  K1 block k<nblk: LDS hist of chunk k -> block-local excl scan -> coalesced
//     offsets row offs[k][0..nbuck] -> scatter keys WITHIN chunk region
//     (bucket-sorted per chunk). Blocks >= nblk: per-node transform -> yq.
//  K2 (pool): per bucket, gather the nblk per-chunk segments into LDS skeys,
//     then R4 readlane/LDS-atomicMax loop + fused BN/dst epilogue.
// ===========================================================================

// --- K1: fused transform + count/local-multisplit --------------------------
__global__ __launch_bounds__(256) void fused_tc_kernel(
    const float* __restrict__ features, const float* __restrict__ node,
    const float* __restrict__ weight, const float* __restrict__ gamma,
    const float* __restrict__ rvar, unsigned short* __restrict__ yq,
    const int* __restrict__ edges, int* __restrict__ offs,
    int* __restrict__ keys,
    int n_nodes, int n_edges, int nbuck, int chunk, int nblk)
{
    __shared__ __align__(16) int smem[MAXBUCK];   // 16 KB, both roles share
    __shared__ int wsum[4];
    const int tid = threadIdx.x;
    if ((int)blockIdx.x < nblk) {
        // ---- count + local multisplit role ----
        int* h = smem;
        for (int i = tid; i < nbuck; i += 256) h[i] = 0;
        __syncthreads();
        const int e0 = blockIdx.x * chunk;            // chunk is even
        const int e1 = min(e0 + chunk, n_edges);
        const int len = (e1 > e0) ? (e1 - e0) : 0;
        const int np = len >> 1;
        const int4* ep4 = (const int4*)(edges + 2 * e0);
        for (int p = tid; p < np; p += 256) {
            int4 v = ep4[p];
            atomicAdd(&h[v.x >> BW_LOG], 1);
            atomicAdd(&h[v.z >> BW_LOG], 1);
        }
        if ((len & 1) && tid == 0)
            atomicAdd(&h[edges[2 * (e1 - 1)] >> BW_LOG], 1);
        __syncthreads();

        // block-local exclusive scan of h[0..nbuck)
        const int SER = (nbuck + 255) / 256;
        const int lo = tid * SER, hi = min(lo + SER, nbuck);
        int sum = 0;
        for (int i = lo; i < hi; ++i) sum += h[i];
        const int lane = tid & 63, wv = tid >> 6;
        int x = sum;
#pragma unroll
        for (int off = 1; off < 64; off <<= 1) {
            int y = __shfl_up(x, off);
            if (lane >= off) x += y;
        }
        if (lane == 63) wsum[wv] = x;
        __syncthreads();
        int wex = 0;
        for (int k = 0; k < wv; ++k) wex += wsum[k];
        int run = wex + x - sum;
        for (int i = lo; i < hi; ++i) { int t = h[i]; h[i] = run; run += t; }
        __syncthreads();

        // coalesced offsets row (before cursors destroy h)
        int* orow = offs + (size_t)blockIdx.x * (nbuck + 1);
        for (int i = tid; i < nbuck; i += 256) orow[i] = h[i];
        if (tid == 0) orow[nbuck] = len;
        __syncthreads();

        // scatter keys within [e0, e1) (h = running cursors)
        for (int p = tid; p < np; p += 256) {
            int4 v = ep4[p];
            const int b0 = v.x >> BW_LOG;
            const int p0 = atomicAdd(&h[b0], 1);
            keys[e0 + p0] = (v.x & (BW - 1)) | (v.y << BW_LOG);
            const int b1 = v.z >> BW_LOG;
            const int p1 = atomicAdd(&h[b1], 1);
            keys[e0 + p1] = (v.z & (BW - 1)) | (v.w << BW_LOG);
        }
        if ((len & 1) && tid == 0) {
            const int dst = edges[2 * (e1 - 1)], src = edges[2 * (e1 - 1) + 1];
            const int pos = atomicAdd(&h[dst >> BW_LOG], 1);
            keys[e0 + pos] = (dst & (BW - 1)) | (src << BW_LOG);
        }
    } else {
        // ---- transform role: LDS-staged tile of 64 nodes x 32 floats ----
        float* stage = (float*)smem;               // 8 KB
        const int lane = tid & 63, wid = tid >> 6;
        const int n0   = ((int)blockIdx.x - nblk) * TNODES;
        const int nrem = min(TNODES, n_nodes - n0);

        for (int idx = tid; idx < nrem * XDIM; idx += 256) {
            const int r = idx >> 5, c = idx & 31;
            float v = (c < IN_DIM) ? features[(size_t)(n0 + r) * IN_DIM + c]
                                   : node[(size_t)(n0 + r) * 3 + (c - IN_DIM)];
            stage[idx] = v;
        }

        const float a = gamma[lane] * __frsqrt_rn(rvar[lane] + BN_EPS);
        float w[XDIM];
        const float4* wp = (const float4*)(weight + lane * XDIM);
#pragma unroll
        for (int q = 0; q < 8; ++q) {
            float4 v = wp[q];
            w[4*q+0] = v.x * a; w[4*q+1] = v.y * a;
            w[4*q+2] = v.z * a; w[4*q+3] = v.w * a;
        }
        __syncthreads();

        const int r0 = wid * (TNODES / 4);
        const int r1 = min(r0 + TNODES / 4, nrem);
        for (int r = r0; r < r1; ++r) {
            const float4* xs = (const float4*)(stage + r * XDIM); // broadcast
            float a0 = 0.f, a1 = 0.f, a2 = 0.f, a3 = 0.f;
#pragma unroll
            for (int q = 0; q < 8; ++q) {
                float4 x4 = xs[q];
                a0 = fmaf(x4.x, w[4*q+0], a0);
                a1 = fmaf(x4.y, w[4*q+1], a1);
                a2 = fmaf(x4.z, w[4*q+2], a2);
                a3 = fmaf(x4.w, w[4*q+3], a3);
            }
            const float acc = (a0 + a1) + (a2 + a3);
            unsigned short hh = __half_as_ushort(__float2half(acc));
            unsigned short enc = (hh & 0x8000) ? (unsigned short)(~hh)
                                               : (unsigned short)(hh | 0x8000);
            yq[(size_t)(n0 + r) * OUT_DIM + lane] = enc;
        }
    }
}

// --- K2: pool. Assemble bucket's per-chunk segments into LDS, then R4 loop -
#define LOADQ(V, D, BASE)                                                     \
    _Pragma("unroll")                                                         \
    for (int u = 0; u < 16; ++u) {                                            \
        const int key = __builtin_amdgcn_readlane(kv, (BASE) + u);            \
        D[u] = key & (BW - 1);                                                \
        V[u] = yq[(size_t)((unsigned)key >> BW_LOG) * OUT_DIM + lane];        \
    }

#define ATOMQ(V, D)                                                           \
    _Pragma("unroll")                                                         \
    for (int u = 0; u < 16; ++u)                                              \
        atomicMax(&acc[D[u] * OUT_DIM + lane], (int)V[u]);

__global__ __launch_bounds__(512, 4) void pool_fused_kernel(
    const int* __restrict__ offs, const int* __restrict__ keys,
    const unsigned short* __restrict__ yq, const float* __restrict__ node,
    const float* __restrict__ weight, const float* __restrict__ gamma,
    const float* __restrict__ beta, const float* __restrict__ rmean,
    const float* __restrict__ rvar,
    float* __restrict__ out, int n_nodes, int nbuck, int chunk, int nblk)
{
    __shared__ int skeys[KCAP];          // 16 KB
    __shared__ int acc[BW * OUT_DIM];    // 8 KB
    __shared__ int sstart[MAXNBLK];      // global start of segment (k,b)
    __shared__ int spref[MAXNBLK + 1];   // excl prefix of segment counts
    const int tid = threadIdx.x;
    const int lane = tid & 63, wid = tid >> 6;
    const int b = blockIdx.x;

    {   // init acc to sentinel
        int4* p = (int4*)acc;
        for (int i = tid; i < BW * OUT_DIM / 4; i += 512)
            p[i] = make_int4(SENT, SENT, SENT, SENT);
    }

    // load segment table: one thread per chunk; [b,b+1] pair is adjacent
    if (tid < nblk) {
        const int* orow = offs + (size_t)tid * (nbuck + 1) + b;
        const int s = orow[0];
        const int e = orow[1];
        sstart[tid] = tid * chunk + s;
        spref[tid]  = e - s;
    }
    __syncthreads();

    // exclusive scan of spref[0..nblk) by wave 0 (nblk <= 128)
    if (wid == 0) {
        int c0 = (lane < nblk) ? spref[lane] : 0;
        int x0 = c0;
#pragma unroll
        for (int off = 1; off < 64; off <<= 1) {
            int y = __shfl_up(x0, off);
            if (lane >= off) x0 += y;
        }
        const int tot0 = __shfl(x0, 63);
        int c1 = (64 + lane < nblk) ? spref[64 + lane] : 0;
        int x1 = c1;
#pragma unroll
        for (int off = 1; off < 64; off <<= 1) {
            int y = __shfl_up(x1, off);
            if (lane >= off) x1 += y;
        }
        const int tot1 = __shfl(x1, 63);
        if (lane < nblk) spref[lane] = x0 - c0;
        if (64 + lane < nblk) spref[64 + lane] = tot0 + x1 - c1;
        if (lane == 0) spref[nblk] = tot0 + tot1;
    }
    __syncthreads();
    const int cnt = spref[nblk];

    if (cnt <= KCAP) {
        // assemble segments into LDS (wave w handles chunks w, w+8, ...)
        for (int k = wid; k < nblk; k += 8) {
            const int bg = sstart[k];
            const int bs = spref[k];
            const int ck = spref[k + 1] - bs;
            for (int j = lane; j < ck; j += 64)
                skeys[bs + j] = keys[bg + j];
        }
        __syncthreads();

        // R4 gather loop from LDS skeys
        const int slice = (cnt + 7) >> 3;
        const int w_beg = wid * slice;
        const int w_end = min(w_beg + slice, cnt);
        if (w_beg < w_end) {
            const int last = w_end - 1;
            int j = w_beg;
            int kv = skeys[min(j + lane, last)];
            while (j < w_end) {
                const int jn = j + 64;
                int kv_n = 0;
                if (jn < w_end) kv_n = skeys[min(jn + lane, last)];

                unsigned int va[16]; int da[16];
                unsigned int vb[16]; int db[16];
                LOADQ(va, da, 0)
                LOADQ(vb, db, 16)
                ATOMQ(va, da)
                LOADQ(va, da, 32)
                ATOMQ(vb, db)
                LOADQ(vb, db, 48)
                ATOMQ(va, da)
                ATOMQ(vb, db)

                j = jn; kv = kv_n;
            }
        }
    } else {
        // fallback (giant bucket): stream segments, wave-wide LDS atomics
        for (int k = wid; k < nblk; k += 8) {
            const int bg = sstart[k];
            const int ck = spref[k + 1] - spref[k];
            for (int j = 0; j < ck; ++j) {
                const int key = keys[bg + j];
                const int d = key & (BW - 1);
                const unsigned int v = yq[(size_t)((unsigned)key >> BW_LOG) * OUT_DIM + lane];
                atomicMax(&acc[d * OUT_DIM + lane], (int)v);
            }
        }
    }
    __syncthreads();

    const float a  = gamma[lane] * __frsqrt_rn(rvar[lane] + BN_EPS);
    const float bp = beta[lane] - rmean[lane] * a;
    const float w29 = weight[lane * XDIM + 29] * a;
    const float w30 = weight[lane * XDIM + 30] * a;
    const float w31 = weight[lane * XDIM + 31] * a;

    for (int d = wid; d < BW; d += 8) {
        const int dg = b * BW + d;
        if (dg >= n_nodes) break;
        const int k = acc[d * OUT_DIM + lane];
        float rr;
        if (k == SENT) {
            rr = 0.0f;
        } else {
            const unsigned short enc = (unsigned short)k;
            const unsigned short h = (enc & 0x8000) ? (unsigned short)(enc ^ 0x8000)
                                                    : (unsigned short)(~enc);
            const float v = __half2float(__ushort_as_half(h));
            const float nx = node[(size_t)dg * 3 + 0];
            const float ny = node[(size_t)dg * 3 + 1];
            const float nz = node[(size_t)dg * 3 + 2];
            rr = v + (bp - (w29 * nx + w30 * ny + w31 * nz));
        }
        out[(size_t)dg * OUT_DIM + lane] = rr;
    }
}

// ===========================================================================
// Fallback path (workspace too small): direct atomic kernels
// ===========================================================================
__global__ void init_kernel(int4* __restrict__ out, int total4) {
    int t = blockIdx.x * blockDim.x + threadIdx.x;
    if (t < total4) out[t] = make_int4(INT_MIN, INT_MIN, INT_MIN, INT_MIN);
}

__global__ __launch_bounds__(256) void edge_atomic_kernel(
    const int* __restrict__ edges,
    const float* __restrict__ features, const float* __restrict__ node,
    const float* __restrict__ weight, const float* __restrict__ gamma,
    const float* __restrict__ beta, const float* __restrict__ rmean,
    const float* __restrict__ rvar,
    int* __restrict__ out, int n_edges, int epw)
{
    const int lane = threadIdx.x & 63;
    const int wave = (blockIdx.x * blockDim.x + threadIdx.x) >> 6;
    int e0 = wave * epw, e1 = e0 + epw;
    if (e1 > n_edges) e1 = n_edges;

    float w[XDIM];
    const float4* wp = (const float4*)(weight + lane * XDIM);
#pragma unroll
    for (int q = 0; q < 8; ++q) {
        float4 v = wp[q];
        w[4*q+0] = v.x; w[4*q+1] = v.y; w[4*q+2] = v.z; w[4*q+3] = v.w;
    }
    const float a = gamma[lane] * __frsqrt_rn(rvar[lane] + BN_EPS);
    const float bprime = beta[lane] - rmean[lane] * a;

    for (int e = e0; e < e1; ++e) {
        const int dst = edges[2*e+0], src = edges[2*e+1];
        float x[XDIM];
#pragma unroll
        for (int i = 0; i < IN_DIM; ++i) x[i] = features[(size_t)src * IN_DIM + i];
#pragma unroll
        for (int j = 0; j < 3; ++j)
            x[IN_DIM+j] = node[(size_t)src*3+j] - node[(size_t)dst*3+j];
        float acc = 0.0f;
#pragma unroll
        for (int i = 0; i < XDIM; ++i) acc = fmaf(x[i], w[i], acc);
        float msg = fmaf(acc, a, bprime);
        int bb = __float_as_int(msg);
        int key = (bb < 0) ? (bb ^ 0x7FFFFFFF) : bb;
        atomicMax(out + (size_t)dst * OUT_DIM + lane, key);
    }
}

__global__ void decode_kernel(int* __restrict__ out, int total) {
    int t = blockIdx.x * blockDim.x + threadIdx.x;
    if (t >= total) return;
    int k = out[t];
    float r;
    if (k == INT_MIN) r = 0.0f;
    else { int b = (k < 0) ? (k ^ 0x7FFFFFFF) : k; r = __int_as_float(b); }
    ((float*)out)[t] = r;
}

// ===========================================================================
extern "C" void kernel_launch(void* const* d_in, const int* in_sizes, int n_in,
                              void* d_out, int out_size, void* d_ws, size_t ws_size,
                              hipStream_t stream) {
    const float* node     = (const float*)d_in[0];
    const float* features = (const float*)d_in[1];
    const int*   edges    = (const int*)d_in[2];
    const float* weight   = (const float*)d_in[3];
    const float* gamma    = (const float*)d_in[4];
    const float* beta     = (const float*)d_in[5];
    const float* rmean    = (const float*)d_in[6];
    const float* rvar     = (const float*)d_in[7];

    const int n_nodes = in_sizes[0] / 3;
    const int n_edges = in_sizes[2] / 2;

    const int nbuck = (n_nodes + BW - 1) >> BW_LOG;       // 3125

    // pick largest NBLK (<= MAXNBLK) whose workspace fits
    int nblk = 0; size_t o_yq=0, o_offs=0, o_keys=0; size_t need = 0;
    for (int cand = MAXNBLK; cand >= 32; cand >>= 1) {
        size_t off = 0;
        auto alloc = [&](size_t bytes) { size_t r = off; off = (off + bytes + 15) & ~(size_t)15; return r; };
        o_yq   = alloc((size_t)n_nodes * OUT_DIM * sizeof(unsigned short));
        o_offs = alloc((size_t)cand * (nbuck + 1) * sizeof(int));
        o_keys = alloc((size_t)n_edges * sizeof(int));
        need = off;
        if (need <= ws_size) { nblk = cand; break; }
    }

    if (nblk > 0 && nbuck <= MAXBUCK && n_nodes <= MAXBUCK * BW) {
        int chunk = (n_edges + nblk - 1) / nblk;
        chunk = (chunk + 1) & ~1;                          // even, for int4 edge loads
        const int ntb = (n_nodes + TNODES - 1) / TNODES;   // transform blocks

        char* base  = (char*)d_ws;
        unsigned short* yq = (unsigned short*)(base + o_yq);
        int* offs   = (int*)(base + o_offs);   // [nblk][nbuck+1]
        int* keys   = (int*)(base + o_keys);   // chunk-organized, bucket-sorted

        fused_tc_kernel<<<nblk + ntb, 256, 0, stream>>>(
            features, node, weight, gamma, rvar, yq,
            edges, offs, keys, n_nodes, n_edges, nbuck, chunk, nblk);
        pool_fused_kernel<<<nbuck, 512, 0, stream>>>(
            offs, keys, yq, node, weight, gamma, beta, rmean, rvar,
            (float*)d_out, n_nodes, nbuck, chunk, nblk);
    } else {
        int* out_i = (int*)d_out;
        const int total4 = out_size / 4;
        init_kernel<<<(total4 + 255) / 256, 256, 0, stream>>>((int4*)out_i, total4);
        const int n_waves = 8192;
        const int epw = (n_edges + n_waves - 1) / n_waves;
        edge_atomic_kernel<<<n_waves / 4, 256, 0, stream>>>(
            edges, features, node, weight, gamma, beta, rmean, rvar,
            out_i, n_edges, epw);
        decode_kernel<<<(out_size + 255) / 256, 256, 0, stream>>>(out_i, out_size);
    }
}

// Round 10
// 184.732 us; speedup vs baseline: 1.0270x; 1.0270x over previous
//
#include <hip/hip_runtime.h>
#include <hip/hip_fp16.h>

#define IN_DIM 29
#define XDIM 32
#define OUT_DIM 64
#define BN_EPS 1e-5f

#define BW      32       // dsts per bucket (LDS tile: 32*64*4 = 8 KB)
#define BW_LOG  5
#define TNODES  64       // nodes per transform block (stage = 64*32*4 = 8 KB)
#define MAXBUCK 4096     // static LDS arrays; n_nodes <= 131072
#define SENT    0        // ordered-u16 sentinel: any real enc > 0

// ===========================================================================
// out[d][o] = max_{src in N(d)} y[src][o] + (beta - a*mean - a*(W[:,29:32].node_d))[o]
// y[n][o] = a[o] * (W[o,:] . [feat_n; node_n]),  a = gamma*rsqrt(var+eps)
// y stored as monotone ordered-u16 fp16 encoding; empty segment -> 0.
// Pipeline: R8 bookkeeping (nblk=128, absolute offsets) + asm-MLP pool.
// ===========================================================================

// --- K1: fused per-node transform (blocks >= nblk) + bucket histogram ------
__global__ __launch_bounds__(256) void fused_tc_kernel(
    const float* __restrict__ features, const float* __restrict__ node,
    const float* __restrict__ weight, const float* __restrict__ gamma,
    const float* __restrict__ rvar, unsigned short* __restrict__ yq,
    const int* __restrict__ edges, int* __restrict__ gHist,
    int n_nodes, int n_edges, int nbuck, int chunk, int nblk)
{
    __shared__ __align__(16) int smem[MAXBUCK];   // 16 KB, both roles share
    if ((int)blockIdx.x < nblk) {
        // ---- count role: int4 = 2 edges per load ----
        int* h = smem;
        for (int i = threadIdx.x; i < nbuck; i += 256) h[i] = 0;
        __syncthreads();
        const int e0 = blockIdx.x * chunk;            // chunk is even
        const int e1 = min(e0 + chunk, n_edges);
        const int np = (e1 - e0) >> 1;
        const int4* ep4 = (const int4*)(edges + 2 * e0);
        for (int p = threadIdx.x; p < np; p += 256) {
            int4 v = ep4[p];
            atomicAdd(&h[v.x >> BW_LOG], 1);
            atomicAdd(&h[v.z >> BW_LOG], 1);
        }
        if (((e1 - e0) & 1) && threadIdx.x == 0)
            atomicAdd(&h[edges[2 * (e1 - 1)] >> BW_LOG], 1);
        __syncthreads();
        for (int i = threadIdx.x; i < nbuck; i += 256)
            gHist[i * nblk + blockIdx.x] = h[i];
    } else {
        // ---- transform role: LDS-staged tile of 64 nodes x 32 floats ----
        float* stage = (float*)smem;               // 8 KB
        const int tid  = threadIdx.x;
        const int lane = tid & 63, wid = tid >> 6;
        const int n0   = ((int)blockIdx.x - nblk) * TNODES;
        const int nrem = min(TNODES, n_nodes - n0);

        for (int idx = tid; idx < nrem * XDIM; idx += 256) {
            const int r = idx >> 5, c = idx & 31;
            float v = (c < IN_DIM) ? features[(size_t)(n0 + r) * IN_DIM + c]
                                   : node[(size_t)(n0 + r) * 3 + (c - IN_DIM)];
            stage[idx] = v;
        }

        const float a = gamma[lane] * __frsqrt_rn(rvar[lane] + BN_EPS);
        float w[XDIM];
        const float4* wp = (const float4*)(weight + lane * XDIM);
#pragma unroll
        for (int q = 0; q < 8; ++q) {
            float4 v = wp[q];
            w[4*q+0] = v.x * a; w[4*q+1] = v.y * a;
            w[4*q+2] = v.z * a; w[4*q+3] = v.w * a;
        }
        __syncthreads();

        const int r0 = wid * (TNODES / 4);
        const int r1 = min(r0 + TNODES / 4, nrem);
        for (int r = r0; r < r1; ++r) {
            const float4* xs = (const float4*)(stage + r * XDIM); // broadcast
            float a0 = 0.f, a1 = 0.f, a2 = 0.f, a3 = 0.f;
#pragma unroll
            for (int q = 0; q < 8; ++q) {
                float4 x = xs[q];
                a0 = fmaf(x.x, w[4*q+0], a0);
                a1 = fmaf(x.y, w[4*q+1], a1);
                a2 = fmaf(x.z, w[4*q+2], a2);
                a3 = fmaf(x.w, w[4*q+3], a3);
            }
            const float acc = (a0 + a1) + (a2 + a3);
            unsigned short hh = __half_as_ushort(__float2half(acc));
            unsigned short enc = (hh & 0x8000) ? (unsigned short)(~hh)
                                               : (unsigned short)(hh | 0x8000);
            yq[(size_t)(n0 + r) * OUT_DIM + lane] = enc;
        }
    }
}

// --- K2: in-place block scan (1024/block) + per-block totals in aux --------
__global__ __launch_bounds__(256) void scan_a_kernel(
    int* __restrict__ data, int n, int* __restrict__ aux)
{
    const int t = threadIdx.x;
    const int base = blockIdx.x * 1024 + t * 4;
    int v[4];
#pragma unroll
    for (int k = 0; k < 4; ++k) v[k] = (base + k < n) ? data[base + k] : 0;
    int tsum = v[0] + v[1] + v[2] + v[3];

    const int lane = t & 63, wv = t >> 6;
    int x = tsum;
#pragma unroll
    for (int off = 1; off < 64; off <<= 1) {
        int y = __shfl_up(x, off);
        if (lane >= off) x += y;
    }
    __shared__ int wsum[4];
    if (lane == 63) wsum[wv] = x;
    __syncthreads();
    int wexcl = 0;
    for (int i = 0; i < wv; ++i) wexcl += wsum[i];
    int run = wexcl + x - tsum;
#pragma unroll
    for (int k = 0; k < 4; ++k) {
        if (base + k < n) data[base + k] = run;
        run += v[k];
    }
    if (t == 255) aux[blockIdx.x] = run;
}

// --- K3: single-block parallel exclusive scan of aux -----------------------
__global__ __launch_bounds__(256) void scan_b_kernel(int* __restrict__ aux, int nb) {
    const int t = threadIdx.x;
    const int lane = t & 63, wv = t >> 6;
    __shared__ int wsum[4];
    __shared__ int s_run;
    if (t == 0) s_run = 0;
    __syncthreads();
    for (int base = 0; base < nb; base += 256) {
        const int i = base + t;
        int v = (i < nb) ? aux[i] : 0;
        int x = v;
#pragma unroll
        for (int off = 1; off < 64; off <<= 1) {
            int y = __shfl_up(x, off);
            if (lane >= off) x += y;
        }
        if (lane == 63) wsum[wv] = x;
        __syncthreads();
        int wexcl = 0;
        for (int k = 0; k < wv; ++k) wexcl += wsum[k];
        const int run = s_run;
        if (i < nb) aux[i] = run + wexcl + x - v;
        __syncthreads();
        if (t == 255) s_run = run + wexcl + x;
        __syncthreads();
    }
}

// --- K3.5: fold aux back in -> ABSOLUTE offsets (coalesced int4) -----------
__global__ __launch_bounds__(256) void scan_fix_kernel(
    int* __restrict__ data, const int* __restrict__ aux, int n)
{
    const int i4 = blockIdx.x * 256 + threadIdx.x;
    const int base = i4 * 4;
    if (base + 3 < n) {
        int4 v = ((int4*)data)[i4];
        const int a = aux[base >> 10];          // 1024-chunk: no 4-pack crossing
        v.x += a; v.y += a; v.z += a; v.w += a;
        ((int4*)data)[i4] = v;
    } else {
        for (int k = base; k < n; ++k) data[k] += aux[k >> 10];
    }
}

// --- K4: multisplit partition -> per-bucket contiguous key runs ------------
__global__ __launch_bounds__(512) void partition_kernel(
    const int* __restrict__ edges, const int* __restrict__ gOffs,
    int* __restrict__ keys, int n_edges, int nbuck, int chunk, int nblk)
{
    __shared__ int cur[MAXBUCK];
    for (int i = threadIdx.x; i < nbuck; i += 512)
        cur[i] = gOffs[i * nblk + blockIdx.x];         // single scattered read
    __syncthreads();
    const int e0 = blockIdx.x * chunk;            // chunk is even
    const int e1 = min(e0 + chunk, n_edges);
    const int np = (e1 - e0) >> 1;
    const int4* ep4 = (const int4*)(edges + 2 * e0);
    for (int p = threadIdx.x; p < np; p += 512) {
        int4 v = ep4[p];
        const int b0 = v.x >> BW_LOG;
        const int p0 = atomicAdd(&cur[b0], 1);
        keys[p0] = (v.x & (BW - 1)) | (v.y << BW_LOG);
        const int b1 = v.z >> BW_LOG;
        const int p1 = atomicAdd(&cur[b1], 1);
        keys[p1] = (v.z & (BW - 1)) | (v.w << BW_LOG);
    }
    if (((e1 - e0) & 1) && threadIdx.x == 0) {
        const int dst = edges[2 * (e1 - 1)], src = edges[2 * (e1 - 1) + 1];
        const int b = dst >> BW_LOG;
        const int pos = atomicAdd(&cur[b], 1);
        keys[pos] = (dst & (BW - 1)) | (src << BW_LOG);
    }
}

// --- K5: fused pool with FORCED memory-level parallelism. ------------------
// All vmcnt ops inside the loop are inline-asm-issued (8-wide ushort gathers
// + 1 keys prefetch), so the counted `s_waitcnt vmcnt(8)` is exact: 16
// gathers guaranteed in flight per wave. Group being consumed is data-tied
// to its waitcnt via "+v" (rule-18-safe: uses depend on tied regs).
#define ADDR8(P, D, BASE)                                                     \
    _Pragma("unroll")                                                         \
    for (int u = 0; u < 8; ++u) {                                             \
        const int key = __builtin_amdgcn_readlane(kv, (BASE) + u);            \
        D[u] = key & (BW - 1);                                                \
        P[u] = yq + (size_t)((unsigned)key >> BW_LOG) * OUT_DIM + lane;       \
    }

#define ISSUE8(R, P)                                                          \
    asm volatile(                                                             \
        "global_load_ushort %0, %[p0], off\n\t"                               \
        "global_load_ushort %1, %[p1], off\n\t"                               \
        "global_load_ushort %2, %[p2], off\n\t"                               \
        "global_load_ushort %3, %[p3], off\n\t"                               \
        "global_load_ushort %4, %[p4], off\n\t"                               \
        "global_load_ushort %5, %[p5], off\n\t"                               \
        "global_load_ushort %6, %[p6], off\n\t"                               \
        "global_load_ushort %7, %[p7], off"                                   \
        : "=&v"(R[0]), "=&v"(R[1]), "=&v"(R[2]), "=&v"(R[3]),                 \
          "=&v"(R[4]), "=&v"(R[5]), "=&v"(R[6]), "=&v"(R[7])                  \
        : [p0]"v"(P[0]), [p1]"v"(P[1]), [p2]"v"(P[2]), [p3]"v"(P[3]),         \
          [p4]"v"(P[4]), [p5]"v"(P[5]), [p6]"v"(P[6]), [p7]"v"(P[7]));

#define WAITVM8(R)                                                            \
    asm volatile("s_waitcnt vmcnt(8)"                                         \
        : "+v"(R[0]), "+v"(R[1]), "+v"(R[2]), "+v"(R[3]),                     \
          "+v"(R[4]), "+v"(R[5]), "+v"(R[6]), "+v"(R[7]));

#define WAITVM0(R, KN)                                                        \
    asm volatile("s_waitcnt vmcnt(0)"                                         \
        : "+v"(R[0]), "+v"(R[1]), "+v"(R[2]), "+v"(R[3]),                     \
          "+v"(R[4]), "+v"(R[5]), "+v"(R[6]), "+v"(R[7]), "+v"(KN));

#define ATOM8(R, D)                                                           \
    _Pragma("unroll")                                                         \
    for (int u = 0; u < 8; ++u)                                               \
        atomicMax(&acc[D[u] * OUT_DIM + lane], (int)R[u]);

__global__ __launch_bounds__(512, 4) void pool_fused_kernel(
    const int* __restrict__ gOffs, const int* __restrict__ keys,
    const unsigned short* __restrict__ yq, const float* __restrict__ node,
    const float* __restrict__ weight, const float* __restrict__ gamma,
    const float* __restrict__ beta, const float* __restrict__ rmean,
    const float* __restrict__ rvar,
    float* __restrict__ out, int n_nodes, int n_edges, int nbuck, int nblk)
{
    __shared__ int acc[BW * OUT_DIM];   // 8 KB
    const int tid = threadIdx.x;
    const int lane = tid & 63, wid = tid >> 6;
    const int b = blockIdx.x;

    {   // init to sentinel 0
        int4* p = (int4*)acc;
        for (int i = tid; i < BW * OUT_DIM / 4; i += 512)
            p[i] = make_int4(SENT, SENT, SENT, SENT);
    }
    __syncthreads();

    const int beg = gOffs[(size_t)b * nblk];
    const int end = (b == nbuck - 1) ? n_edges : gOffs[(size_t)(b + 1) * nblk];

    const int cnt = end - beg;
    const int slice = (cnt + 7) >> 3;          // per-wave contiguous slice (8 waves)
    const int w_beg = beg + wid * slice;
    const int w_end = min(w_beg + slice, end);

    if (w_beg < w_end) {
        const int last = w_end - 1;
        int j = w_beg;
        int kv = keys[min(j + lane, last)];    // 64 keys (clamped pad, same bucket)
        while (j < w_end) {
            const int jn = j + 64;
            int kvn = 0;
            if (jn < w_end) {                  // wave-uniform branch
                const int* kp = keys + min(jn + lane, last);
                asm volatile("global_load_dword %0, %1, off"
                             : "=&v"(kvn) : "v"(kp));
            }

            const unsigned short* pA[8]; int dA[8]; unsigned int rA[8];
            const unsigned short* pB[8]; int dB[8]; unsigned int rB[8];

            ADDR8(pA, dA, 0)   ISSUE8(rA, pA)
            ADDR8(pB, dB, 8)   ISSUE8(rB, pB)
            WAITVM8(rA)        ATOM8(rA, dA)
            ADDR8(pA, dA, 16)  ISSUE8(rA, pA)
            WAITVM8(rB)        ATOM8(rB, dB)
            ADDR8(pB, dB, 24)  ISSUE8(rB, pB)
            WAITVM8(rA)        ATOM8(rA, dA)
            ADDR8(pA, dA, 32)  ISSUE8(rA, pA)
            WAITVM8(rB)        ATOM8(rB, dB)
            ADDR8(pB, dB, 40)  ISSUE8(rB, pB)
            WAITVM8(rA)        ATOM8(rA, dA)
            ADDR8(pA, dA, 48)  ISSUE8(rA, pA)
            WAITVM8(rB)        ATOM8(rB, dB)
            ADDR8(pB, dB, 56)  ISSUE8(rB, pB)
            WAITVM8(rA)        ATOM8(rA, dA)
            WAITVM0(rB, kvn)   ATOM8(rB, dB)

            j = jn; kv = kvn;
        }
    }
    __syncthreads();

    const float a  = gamma[lane] * __frsqrt_rn(rvar[lane] + BN_EPS);
    const float bp = beta[lane] - rmean[lane] * a;
    const float w29 = weight[lane * XDIM + 29] * a;
    const float w30 = weight[lane * XDIM + 30] * a;
    const float w31 = weight[lane * XDIM + 31] * a;

    for (int d = wid; d < BW; d += 8) {
        const int dg = b * BW + d;
        if (dg >= n_nodes) break;
        const int k = acc[d * OUT_DIM + lane];
        float rr;
        if (k == SENT) {
            rr = 0.0f;
        } else {
            const unsigned short enc = (unsigned short)k;
            const unsigned short h = (enc & 0x8000) ? (unsigned short)(enc ^ 0x8000)
                                                    : (unsigned short)(~enc);
            const float v = __half2float(__ushort_as_half(h));
            const float nx = node[(size_t)dg * 3 + 0];
            const float ny = node[(size_t)dg * 3 + 1];
            const float nz = node[(size_t)dg * 3 + 2];
            rr = v + (bp - (w29 * nx + w30 * ny + w31 * nz));
        }
        out[(size_t)dg * OUT_DIM + lane] = rr;
    }
}

// ===========================================================================
// Fallback path (workspace too small): direct atomic kernels
// ===========================================================================
__global__ void init_kernel(int4* __restrict__ out, int total4) {
    int t = blockIdx.x * blockDim.x + threadIdx.x;
    if (t < total4) out[t] = make_int4(INT_MIN, INT_MIN, INT_MIN, INT_MIN);
}

__global__ __launch_bounds__(256) void edge_atomic_kernel(
    const int* __restrict__ edges,
    const float* __restrict__ features, const float* __restrict__ node,
    const float* __restrict__ weight, const float* __restrict__ gamma,
    const float* __restrict__ beta, const float* __restrict__ rmean,
    const float* __restrict__ rvar,
    int* __restrict__ out, int n_edges, int epw)
{
    const int lane = threadIdx.x & 63;
    const int wave = (blockIdx.x * blockDim.x + threadIdx.x) >> 6;
    int e0 = wave * epw, e1 = e0 + epw;
    if (e1 > n_edges) e1 = n_edges;

    float w[XDIM];
    const float4* wp = (const float4*)(weight + lane * XDIM);
#pragma unroll
    for (int q = 0; q < 8; ++q) {
        float4 v = wp[q];
        w[4*q+0] = v.x; w[4*q+1] = v.y; w[4*q+2] = v.z; w[4*q+3] = v.w;
    }
    const float a = gamma[lane] * __frsqrt_rn(rvar[lane] + BN_EPS);
    const float bprime = beta[lane] - rmean[lane] * a;

    for (int e = e0; e < e1; ++e) {
        const int dst = edges[2*e+0], src = edges[2*e+1];
        float x[XDIM];
#pragma unroll
        for (int i = 0; i < IN_DIM; ++i) x[i] = features[(size_t)src * IN_DIM + i];
#pragma unroll
        for (int j = 0; j < 3; ++j)
            x[IN_DIM+j] = node[(size_t)src*3+j] - node[(size_t)dst*3+j];
        float acc = 0.0f;
#pragma unroll
        for (int i = 0; i < XDIM; ++i) acc = fmaf(x[i], w[i], acc);
        float msg = fmaf(acc, a, bprime);
        int bb = __float_as_int(msg);
        int key = (bb < 0) ? (bb ^ 0x7FFFFFFF) : bb;
        atomicMax(out + (size_t)dst * OUT_DIM + lane, key);
    }
}

__global__ void decode_kernel(int* __restrict__ out, int total) {
    int t = blockIdx.x * blockDim.x + threadIdx.x;
    if (t >= total) return;
    int k = out[t];
    float r;
    if (k == INT_MIN) r = 0.0f;
    else { int b = (k < 0) ? (k ^ 0x7FFFFFFF) : k; r = __int_as_float(b); }
    ((float*)out)[t] = r;
}

// ===========================================================================
extern "C" void kernel_launch(void* const* d_in, const int* in_sizes, int n_in,
                              void* d_out, int out_size, void* d_ws, size_t ws_size,
                              hipStream_t stream) {
    const float* node     = (const float*)d_in[0];
    const float* features = (const float*)d_in[1];
    const int*   edges    = (const int*)d_in[2];
    const float* weight   = (const float*)d_in[3];
    const float* gamma    = (const float*)d_in[4];
    const float* beta     = (const float*)d_in[5];
    const float* rmean    = (const float*)d_in[6];
    const float* rvar     = (const float*)d_in[7];

    const int n_nodes = in_sizes[0] / 3;
    const int n_edges = in_sizes[2] / 2;

    const int nbuck = (n_nodes + BW - 1) >> BW_LOG;       // 3125

    // pick largest NBLK whose workspace fits; 128 = measured-best overhead
    int nblk = 0; size_t o_yq=0, o_hist=0, o_aux=0, o_keys=0; size_t need = 0;
    for (int cand = 128; cand >= 32; cand >>= 1) {
        const int n_scan = nbuck * cand;
        const int nb_scan = (n_scan + 1023) / 1024;
        size_t off = 0;
        auto alloc = [&](size_t bytes) { size_t r = off; off = (off + bytes + 15) & ~(size_t)15; return r; };
        o_yq   = alloc((size_t)n_nodes * OUT_DIM * sizeof(unsigned short));
        o_hist = alloc((size_t)n_scan * sizeof(int));
        o_aux  = alloc((size_t)nb_scan * sizeof(int));
        o_keys = alloc((size_t)n_edges * sizeof(int));
        need = off;
        if (need <= ws_size) { nblk = cand; break; }
    }

    if (nblk > 0 && nbuck <= MAXBUCK && n_nodes <= MAXBUCK * BW) {
        const int n_scan = nbuck * nblk;
        const int nb_scan = (n_scan + 1023) / 1024;
        int chunk = (n_edges + nblk - 1) / nblk;
        chunk = (chunk + 1) & ~1;                          // even, for int4 edge loads
        const int ntb = (n_nodes + TNODES - 1) / TNODES;   // transform blocks

        char* base  = (char*)d_ws;
        unsigned short* yq = (unsigned short*)(base + o_yq);
        int* gHist  = (int*)(base + o_hist);   // becomes ABSOLUTE gOffs after scans
        int* aux    = (int*)(base + o_aux);
        int* keys   = (int*)(base + o_keys);

        fused_tc_kernel<<<nblk + ntb, 256, 0, stream>>>(
            features, node, weight, gamma, rvar, yq,
            edges, gHist, n_nodes, n_edges, nbuck, chunk, nblk);
        scan_a_kernel<<<nb_scan, 256, 0, stream>>>(gHist, n_scan, aux);
        scan_b_kernel<<<1, 256, 0, stream>>>(aux, nb_scan);
        scan_fix_kernel<<<(n_scan/4 + 255) / 256, 256, 0, stream>>>(gHist, aux, n_scan);
        partition_kernel<<<nblk, 512, 0, stream>>>(edges, gHist, keys,
                                                   n_edges, nbuck, chunk, nblk);
        pool_fused_kernel<<<nbuck, 512, 0, stream>>>(
            gHist, keys, yq, node, weight, gamma, beta, rmean, rvar,
            (float*)d_out, n_nodes, n_edges, nbuck, nblk);
    } else {
        int* out_i = (int*)d_out;
        const int total4 = out_size / 4;
        init_kernel<<<(total4 + 255) / 256, 256, 0, stream>>>((int4*)out_i, total4);
        const int n_waves = 8192;
        const int epw = (n_edges + n_waves - 1) / n_waves;
        edge_atomic_kernel<<<n_waves / 4, 256, 0, stream>>>(
            edges, features, node, weight, gamma, beta, rmean, rvar,
            out_i, n_edges, epw);
        decode_kernel<<<(out_size + 255) / 256, 256, 0, stream>>>(out_i, out_size);
    }
}